// Round 16
// baseline (82.562 us; speedup 1.0000x reference)
//
#include <hip/hip_runtime.h>
#include <hip/hip_bf16.h>

// Problem constants
#define NB   256
#define NC   4096
#define NG   512
#define NH   128
#define NELEM (NB*NC)            // 1048576
#define LDX  66                  // row stride of x_with_meta in floats
#define NEGV (-1000000000.0f)
#define TILES 16                 // iterations: 8 waves x 32 rows x 16 = 4096 rows/block

typedef __attribute__((ext_vector_type(8))) short short8;
typedef __attribute__((ext_vector_type(4))) float f32x4;

// truncating f32->bf16 pair pack
__device__ __forceinline__ unsigned pack2(float x, float y) {
    return (__float_as_uint(y) & 0xFFFF0000u) | (__float_as_uint(x) >> 16);
}
__device__ __forceinline__ unsigned short f2bf(float f) {   // RNE, weights only
    unsigned u = __float_as_uint(f);
    return (unsigned short)((u + 0x7FFFu + ((u >> 16) & 1u)) >> 16);
}
__device__ __forceinline__ unsigned encf(float f) {         // order-preserving f32->u32
    unsigned u = __float_as_uint(f);
    return (u & 0x80000000u) ? ~u : (u | 0x80000000u);
}
__device__ __forceinline__ float decf(unsigned u) {
    unsigned v = (u & 0x80000000u) ? (u ^ 0x80000000u) : ~u;
    return __uint_as_float(v);
}
__device__ __forceinline__ f32x4 mfma_bf16(short8 a, short8 b, f32x4 c) {
    return __builtin_amdgcn_mfma_f32_16x16x32_bf16(a, b, c, 0, 0, 0);
}
__device__ __forceinline__ f32x4 mfma_fp8(long a, long b, f32x4 c) {
    return __builtin_amdgcn_mfma_f32_16x16x32_fp8_fp8(a, b, c, 0, 0, 0);
}

// async global->LDS, 16B per lane, LDS dest = uniform base + lane*16
__device__ __forceinline__ void gload16(const float* g, float* lds) {
    __builtin_amdgcn_global_load_lds(
        (const __attribute__((address_space(1))) void*)g,
        (__attribute__((address_space(3))) void*)lds,
        16, 0, 0);
}

// ---- single kernel: weight prep + MLP + segment stats + bias MLP + writeout --
// One block (512 thr = 8 waves) per batch row. r15 structure with a half-tile
// counted-vmcnt pipeline: per 32-row tile, gload chunk A (rows 0-15) feeds rg=0
// and chunk B (rows 16-31) feeds rg=1. Issue order per tile: [A',(mid) B',M'];
// top wait vmcnt(5) = A landed (B+M fly), mid wait vmcnt(5) = B landed (M+A'
// fly). The VMEM queue never drains -> memory duty cycle stays high.
__global__ __launch_bounds__(512, 2) void k_fused(
        const float* __restrict__ X,
        const float* __restrict__ W0, const float* __restrict__ W1,
        const float* __restrict__ b0, const float* __restrict__ b1,
        const float* __restrict__ W2, const float* __restrict__ b2p,
        const float* __restrict__ Wb0, const float* __restrict__ bb0,
        const float* __restrict__ Wb1, const float* __restrict__ bb1,
        float* __restrict__ out) {
    __shared__ __align__(16) unsigned char sW1f[16384];     // 16 KB W1 fp8 frags (swizzled)
    __shared__ __align__(16) float sFeat[8][2048];          // 8 KB/wave feats f32 (src-swizzled)
    __shared__ __align__(16) unsigned char sHs[8][4096];    // 4 KB/wave fp8 Hs (dedicated)
    __shared__ float sB0[128];
    __shared__ float sB1W2[256];                            // [0..127]=b1, [128..255]=W2
    __shared__ __align__(16) float sraw[4096];              // 16 KB: W0T scratch, then raw
    __shared__ unsigned short smc[4096];                    // 8 KB meta codes (LDS only)
    __shared__ unsigned scnt[512];
    __shared__ float    ssum[512];
    __shared__ unsigned smx[512];
    __shared__ float    sdelta[512];
    __shared__ unsigned char smulti[512];

    const int t = threadIdx.x, w = t >> 6, l = t & 63;
    const int l15 = l & 15, g = l >> 4;
    const int rx = l15 & 7;
    const int b = blockIdx.x;

    float* fw = sFeat[w];
    unsigned char* hs = sHs[w];
    const size_t rowwave0 = (size_t)b * NC + w * 32;
    const int lrow0 = w * 32;

    // per-lane gload source offsets (floats): row-in-chunk r4, slot sl, swizzled
    const int r4 = l >> 4, sl = l & 15;
    const int offE = r4 * LDX + ((sl ^ r4) << 2);
    const int offO = r4 * LDX + ((sl ^ (r4 + 4)) << 2);

    // ---- FIRST: issue tile-0 staging [A(4), B(4), M(1)] (overlaps weight prep)
    {
        const float* gb = X + rowwave0 * LDX;
#pragma unroll
        for (int k = 0; k < 8; ++k)
            gload16(gb + k * 4 * LDX + ((k & 1) ? offO : offE), fw + k * 256);
    }
    float2 mt = make_float2(0.f, 0.f), mtN = make_float2(0.f, 0.f);
    if (l < 32) mt = *(const float2*)(X + (rowwave0 + l) * LDX + 64);
    __builtin_amdgcn_sched_barrier(0);

    // ---- in-block weight prep ----
    // W0 -> bf16 W0T layout [j][k] into sraw scratch (16 KB, dead until tile-0 epi)
    unsigned short* sW0s = (unsigned short*)sraw;
    {
        const int j = t & 127, kq = t >> 7;                 // k-range [kq*16, kq*16+16)
        unsigned pk[8];
#pragma unroll
        for (int kk = 0; kk < 16; kk += 2) {
            float v0 = W0[(kq * 16 + kk)     * NH + j];
            float v1 = W0[(kq * 16 + kk + 1) * NH + j];
            pk[kk >> 1] = (unsigned)f2bf(v0) | ((unsigned)f2bf(v1) << 16);
        }
        unsigned short* dst = sW0s + j * 64 + kq * 16;
        ((uint4*)dst)[0] = make_uint4(pk[0], pk[1], pk[2], pk[3]);
        ((uint4*)dst)[1] = make_uint4(pk[4], pk[5], pk[6], pk[7]);
    }
    // W1 -> fp8 e4m3, unit-swizzled (u' = u ^ (j&7)), directly into sW1f
#pragma unroll
    for (int it = 0; it < 4; ++it) {
        const int j = t & 127, u = (t >> 7) + it * 4;
        float v[8];
#pragma unroll
        for (int d = 0; d < 8; ++d) v[d] = W1[(u * 8 + d) * NH + j];
        unsigned lo = (unsigned)__builtin_amdgcn_cvt_pk_fp8_f32(v[0], v[1], 0, false);
        lo = (unsigned)__builtin_amdgcn_cvt_pk_fp8_f32(v[2], v[3], (int)lo, true);
        unsigned hi = (unsigned)__builtin_amdgcn_cvt_pk_fp8_f32(v[4], v[5], 0, false);
        hi = (unsigned)__builtin_amdgcn_cvt_pk_fp8_f32(v[6], v[7], (int)hi, true);
        *(uint2*)(sW1f + (j * 16 + (u ^ (j & 7))) * 8) = make_uint2(lo, hi);
    }
    if (t < 128) { sB0[t] = b0[t]; sB1W2[t] = b1[t]; sB1W2[128 + t] = W2[t]; }
    scnt[t] = 0u; ssum[t] = 0.f; smx[t] = 0u;
    const float b2v = b2p[0];

    __syncthreads();   // conversions + biases + seg-init visible

    // loop-invariant W0 fragments from LDS scratch (32 VGPRs)
    short8 w0f[8][2];
#pragma unroll
    for (int n = 0; n < 8; ++n)
#pragma unroll
        for (int kk = 0; kk < 2; ++kk)
            w0f[n][kk] = *(const short8*)(sW0s + (n * 16 + l15) * 64 + kk * 32 + g * 8);

    __syncthreads();   // all w0f reads done before sraw is overwritten by raws

    for (int tau = 0; tau < TILES; ++tau) {
        const size_t rowb = rowwave0 + (size_t)tau * 256;   // 8 waves x 32 rows stride
        const int lrow = lrow0 + tau * 256;

        // ---- wait half-A (4 oldest); B(4)+M(1) remain in flight ----
        asm volatile("s_waitcnt vmcnt(5)" ::: "memory");
        __builtin_amdgcn_sched_barrier(0);

        // bfr-A: rows l15 (half A), pack to bf16
        short8 bfrA[2];
#pragma unroll
        for (int kk = 0; kk < 2; ++kk) {
            const int u0 = kk * 8 + 2 * g;
            const float* base = fw + l15 * 64;
            float4 fa = *(const float4*)(base + ((u0 ^ rx) << 2));
            float4 fb = *(const float4*)(base + (((u0 + 1) ^ rx) << 2));
            union { unsigned u[4]; short8 s; } tu;
            tu.u[0] = pack2(fa.x, fa.y); tu.u[1] = pack2(fa.z, fa.w);
            tu.u[2] = pack2(fb.x, fb.y); tu.u[3] = pack2(fb.z, fb.w);
            bfrA[kk] = tu.s;
        }
        asm volatile("s_waitcnt lgkmcnt(0)" ::: "memory");
        __builtin_amdgcn_sched_barrier(0);
        if (tau + 1 < TILES) {      // issue A'(t+1): fw rows 0-15 now free
            const float* gb = X + (rowb + 256) * LDX;
#pragma unroll
            for (int k = 0; k < 4; ++k)
                gload16(gb + k * 4 * LDX + ((k & 1) ? offO : offE), fw + k * 256);
        }
        __builtin_amdgcn_sched_barrier(0);

        // GEMM1 rg=0 (two n-halves) -> fp8 Hs rows 0-15 (B transfer hides here)
#pragma unroll
        for (int nh = 0; nh < 2; ++nh) {
            f32x4 acc[4];
#pragma unroll
            for (int n4 = 0; n4 < 4; ++n4) acc[n4] = (f32x4){0.f, 0.f, 0.f, 0.f};
#pragma unroll
            for (int n4 = 0; n4 < 4; ++n4) {
                const int n = nh * 4 + n4;
                acc[n4] = mfma_bf16(w0f[n][0], bfrA[0], acc[n4]);
                acc[n4] = mfma_bf16(w0f[n][1], bfrA[1], acc[n4]);
            }
#pragma unroll
            for (int n4 = 0; n4 < 4; ++n4) {
                const int n = nh * 4 + n4;
                const int c0 = n * 16 + g * 4;
                const float bv0 = sB0[c0], bv1 = sB0[c0+1], bv2 = sB0[c0+2], bv3 = sB0[c0+3];
                const int u = (2 * n + (g >> 1)) ^ rx;
                unsigned d0 = (unsigned)__builtin_amdgcn_cvt_pk_fp8_f32(
                    fmaxf(acc[n4][0] + bv0, 0.f), fmaxf(acc[n4][1] + bv1, 0.f), 0, false);
                d0 = (unsigned)__builtin_amdgcn_cvt_pk_fp8_f32(
                    fmaxf(acc[n4][2] + bv2, 0.f), fmaxf(acc[n4][3] + bv3, 0.f), (int)d0, true);
                *(unsigned*)(hs + (l15 * 16 + u) * 8 + (g & 1) * 4) = d0;
            }
        }

        // ---- wait half-B: remaining = M(1)+A'(4) -> vmcnt(5); last tile: M only
        if (tau + 1 < TILES) asm volatile("s_waitcnt vmcnt(5)" ::: "memory");
        else                 asm volatile("s_waitcnt vmcnt(1)" ::: "memory");
        __builtin_amdgcn_sched_barrier(0);

        // bfr-B: rows 16+l15 (half B)
        short8 bfrB[2];
#pragma unroll
        for (int kk = 0; kk < 2; ++kk) {
            const int u0 = kk * 8 + 2 * g;
            const float* base = fw + (16 + l15) * 64;
            float4 fa = *(const float4*)(base + ((u0 ^ rx) << 2));
            float4 fb = *(const float4*)(base + (((u0 + 1) ^ rx) << 2));
            union { unsigned u[4]; short8 s; } tu;
            tu.u[0] = pack2(fa.x, fa.y); tu.u[1] = pack2(fa.z, fa.w);
            tu.u[2] = pack2(fb.x, fb.y); tu.u[3] = pack2(fb.z, fb.w);
            bfrB[kk] = tu.s;
        }
        asm volatile("s_waitcnt lgkmcnt(0)" ::: "memory");
        __builtin_amdgcn_sched_barrier(0);
        if (tau + 1 < TILES) {      // issue B'(t+1) + meta'
            const float* gb = X + (rowb + 256) * LDX;
#pragma unroll
            for (int k = 4; k < 8; ++k)
                gload16(gb + k * 4 * LDX + ((k & 1) ? offO : offE), fw + k * 256);
            if (l < 32) mtN = *(const float2*)(X + (rowb + 256 + l) * LDX + 64);
        }
        __builtin_amdgcn_sched_barrier(0);

        // GEMM1 rg=1 -> fp8 Hs rows 16-31
#pragma unroll
        for (int nh = 0; nh < 2; ++nh) {
            f32x4 acc[4];
#pragma unroll
            for (int n4 = 0; n4 < 4; ++n4) acc[n4] = (f32x4){0.f, 0.f, 0.f, 0.f};
#pragma unroll
            for (int n4 = 0; n4 < 4; ++n4) {
                const int n = nh * 4 + n4;
                acc[n4] = mfma_bf16(w0f[n][0], bfrB[0], acc[n4]);
                acc[n4] = mfma_bf16(w0f[n][1], bfrB[1], acc[n4]);
            }
#pragma unroll
            for (int n4 = 0; n4 < 4; ++n4) {
                const int n = nh * 4 + n4;
                const int c0 = n * 16 + g * 4;
                const float bv0 = sB0[c0], bv1 = sB0[c0+1], bv2 = sB0[c0+2], bv3 = sB0[c0+3];
                const int u = (2 * n + (g >> 1)) ^ rx;
                unsigned d0 = (unsigned)__builtin_amdgcn_cvt_pk_fp8_f32(
                    fmaxf(acc[n4][0] + bv0, 0.f), fmaxf(acc[n4][1] + bv1, 0.f), 0, false);
                d0 = (unsigned)__builtin_amdgcn_cvt_pk_fp8_f32(
                    fmaxf(acc[n4][2] + bv2, 0.f), fmaxf(acc[n4][3] + bv3, 0.f), (int)d0, true);
                *(unsigned*)(hs + ((16 + l15) * 16 + u) * 8 + (g & 1) * 4) = d0;
            }
        }

        // compiler memory barrier: Hs written as unsigned*, read as long* (TBAA
        // no-alias) -- without this the a2 reads may be hoisted above the writes.
        asm volatile("" ::: "memory");

        // A2 fragments (fp8, swizzled) from dedicated Hs
        long a2[2][4];
#pragma unroll
        for (int rg = 0; rg < 2; ++rg)
#pragma unroll
            for (int kk = 0; kk < 4; ++kk)
                a2[rg][kk] = *(const long*)(hs + ((rg * 16 + l15) * 16 + ((kk * 4 + g) ^ rx)) * 8);

        // GEMM2 (fp8) + fused epilogue dot (overlaps in-flight staging)
        float rq[2][4] = {{0.f,0.f,0.f,0.f},{0.f,0.f,0.f,0.f}};
#pragma unroll
        for (int n = 0; n < 8; ++n) {
            f32x4 acc2[2] = {(f32x4){0.f,0.f,0.f,0.f}, (f32x4){0.f,0.f,0.f,0.f}};
            const unsigned char* wrow = sW1f + (n * 16 + l15) * 128;
#pragma unroll
            for (int kk = 0; kk < 4; ++kk) {
                long bb = *(const long*)(wrow + ((kk * 4 + g) ^ rx) * 8);
                acc2[0] = mfma_fp8(a2[0][kk], bb, acc2[0]);
                acc2[1] = mfma_fp8(a2[1][kk], bb, acc2[1]);
            }
            const float b1v = sB1W2[n * 16 + l15], w2v = sB1W2[128 + n * 16 + l15];
#pragma unroll
            for (int rg = 0; rg < 2; ++rg)
#pragma unroll
                for (int q = 0; q < 4; ++q)
                    rq[rg][q] += fmaxf(acc2[rg][q] + b1v, 0.f) * w2v;
        }

        // reduce over l15, store raw + mcode to LDS (no global traffic)
#pragma unroll
        for (int off = 1; off < 16; off <<= 1)
#pragma unroll
            for (int rg = 0; rg < 2; ++rg)
#pragma unroll
                for (int q = 0; q < 4; ++q)
                    rq[rg][q] += __shfl_xor(rq[rg][q], off, 64);
        if (l15 == 0) {
#pragma unroll
            for (int rg = 0; rg < 2; ++rg) {
                const int lm0 = lrow + rg * 16 + g * 4;
                *(float4*)(sraw + lm0) = make_float4(rq[rg][0] + b2v, rq[rg][1] + b2v,
                                                     rq[rg][2] + b2v, rq[rg][3] + b2v);
            }
        }
        if (l < 32) {
            const unsigned pmcu = ((unsigned)((int)mt.x + 1) << 1) | (mt.y > 0.f ? 1u : 0u);
            smc[lrow + l] = (unsigned short)pmcu;
        }
        mt = mtN;
    }

    __syncthreads();   // all raw/mcode in LDS

    // ---- segment reduction (LDS atomics over 512 segs) ----
#pragma unroll
    for (int it = 0; it < 8; ++it) {
        int m = it * 512 + t;
        unsigned c = smc[m];
        if ((c & 1u) && (c >> 1)) {
            int s = (int)(c >> 1) - 1;
            float r = sraw[m];
            atomicAdd(&scnt[s], 1u);
            atomicAdd(&ssum[s], r);
            atomicMax(&smx[s], encf(r));
        }
    }
    __syncthreads();

    // ---- per-seg bias MLP (thread t owns seg t): delta = 0.5*max - mean + bias
    {
        unsigned c = scnt[t];
        float delta = 0.f; unsigned char multi = 0;
        if (c > 1) {
            float smaxv = decf(smx[t]);
            float mean = ssum[t] / (float)c;
            float bias = bb1[0];
#pragma unroll
            for (int j = 0; j < 32; ++j) {
                float h = smaxv * Wb0[j] + mean * Wb0[32 + j] + (float)c * Wb0[64 + j] + bb0[j];
                bias += fmaxf(h, 0.f) * Wb1[j];
            }
            delta = 0.5f * smaxv - mean + bias;
            multi = 1;
        }
        sdelta[t] = delta; smulti[t] = multi;
    }
    __syncthreads();

    // ---- fair/mask writeout (coalesced float4) ----
    const size_t gbase = (size_t)b * NC;
#pragma unroll
    for (int it = 0; it < 2; ++it) {
        int i = it * 512 + t;           // float4 group within row
        int m0 = i * 4;
        float4 rv = *(const float4*)(sraw + m0);
        const float r[4] = {rv.x, rv.y, rv.z, rv.w};
        float fair[4], msk[4];
#pragma unroll
        for (int j = 0; j < 4; ++j) {
            unsigned c = smc[m0 + j];
            msk[j] = (c & 1u) ? 1.0f : 0.0f;
            float f;
            if (c & 1u) {
                f = r[j];
                if (c >> 1) {
                    int s = (int)(c >> 1) - 1;
                    if (smulti[s]) f = 1.5f * r[j] + sdelta[s];
                }
            } else {
                f = NEGV;
            }
            fair[j] = f;
        }
        *(float4*)(out + gbase + m0) = make_float4(fair[0], fair[1], fair[2], fair[3]);
        *(float4*)(out + NELEM + gbase + m0) = make_float4(msk[0], msk[1], msk[2], msk[3]);
    }
}

// ---- launch ----------------------------------------------------------------
extern "C" void kernel_launch(void* const* d_in, const int* in_sizes, int n_in,
                              void* d_out, int out_size, void* d_ws, size_t ws_size,
                              hipStream_t stream) {
    const float* X   = (const float*)d_in[0];
    const float* W0  = (const float*)d_in[1];
    const float* b0  = (const float*)d_in[2];
    const float* W1  = (const float*)d_in[3];
    const float* b1  = (const float*)d_in[4];
    const float* W2  = (const float*)d_in[5];
    const float* b2  = (const float*)d_in[6];
    const float* Wb0 = (const float*)d_in[7];
    const float* bb0 = (const float*)d_in[8];
    const float* Wb1 = (const float*)d_in[9];
    const float* bb1 = (const float*)d_in[10];

    k_fused<<<NB, 512, 0, stream>>>(X, W0, W1, b0, b1, W2, b2,
                                    Wb0, bb0, Wb1, bb1, (float*)d_out);
}